// Round 3
// baseline (116.308 us; speedup 1.0000x reference)
//
#include <hip/hip_runtime.h>
#include <hip/hip_bf16.h>

// Interpolator == attention: out = softmax_c(z_t^T (W+W^T) z_c - q_cc[c]) @ y_context
// Q = log2e * z_target @ (W+W^T)  (split hi/lo bf16)
// K = z_context                   (split hi/lo bf16)
// bias[c] = -log2e * z_c^T W z_c  (f32)
// V^T bf16 [32][8192] for MFMA B-operand column access.

typedef float f32x4 __attribute__((ext_vector_type(4)));
typedef __bf16 bf16x8 __attribute__((ext_vector_type(8)));

#define LOG2E 1.4426950408889634f

static __device__ __forceinline__ unsigned short f2bf(float x) {
  unsigned u = __float_as_uint(x);
  u += 0x7fffu + ((u >> 16) & 1u);   // RNE
  return (unsigned short)(u >> 16);
}
static __device__ __forceinline__ float bf2f(unsigned short h) {
  return __uint_as_float(((unsigned)h) << 16);
}
static __device__ __forceinline__ bf16x8 ldg8(const unsigned short* p) {
  uint4 u = *reinterpret_cast<const uint4*>(p);
  return __builtin_bit_cast(bf16x8, u);
}
static __device__ __forceinline__ unsigned cvt_pk_bf16(float lo, float hi) {
  unsigned r;
  asm("v_cvt_pk_bf16_f32 %0, %1, %2" : "=v"(r) : "v"(lo), "v"(hi));
  return r;
}

__global__ void prep_kernel(const float* __restrict__ zc, const float* __restrict__ yc,
                            const float* __restrict__ zt, const float* __restrict__ W,
                            unsigned short* __restrict__ Qh, unsigned short* __restrict__ Ql,
                            unsigned short* __restrict__ Kh, unsigned short* __restrict__ Kl,
                            unsigned short* __restrict__ Vt, float* __restrict__ bias)
{
  int b = blockIdx.x, tid = threadIdx.x;
  if (b < 2048) {                       // Q = log2e * z_t @ (W+W^T), hi/lo split
    int idx = b * 256 + tid;
    int t = idx >> 6, d = idx & 63;
    const float* z = zt + t * 64;
    float q = 0.f;
    #pragma unroll 8
    for (int k = 0; k < 64; ++k) q = fmaf(z[k], W[k * 64 + d] + W[d * 64 + k], q);
    q *= LOG2E;
    unsigned short h = f2bf(q);
    Qh[idx] = h;
    Ql[idx] = f2bf(q - bf2f(h));
  } else if (b < 4096) {                // K hi/lo split
    int idx = (b - 2048) * 256 + tid;
    float v = zc[idx];
    unsigned short h = f2bf(v);
    Kh[idx] = h;
    Kl[idx] = f2bf(v - bf2f(h));
  } else if (b < 6144) {                // bias[c] = -log2e * z_c^T W z_c, one wave per c
    int c = (b - 4096) * 4 + (tid >> 6), j = tid & 63;
    const float* z = zc + c * 64;
    float cs = 0.f;
    #pragma unroll 8
    for (int i = 0; i < 64; ++i) cs = fmaf(z[i], W[i * 64 + j], cs);
    float part = cs * z[j];
    #pragma unroll
    for (int off = 32; off >= 1; off >>= 1) part += __shfl_xor(part, off, 64);
    if (j == 0) bias[c] = -LOG2E * part;
  } else {                              // V^T bf16
    int idx = (b - 6144) * 256 + tid;
    int dy = idx >> 13, c = idx & 8191;
    Vt[dy * 8192 + c] = f2bf(yc[c * 32 + dy]);
  }
}

// 256 blocks x 512 threads. Block owns 32 targets; wave w owns contexts [w*1024,(w+1)*1024).
// Per 32-context tile: S^T = mfma(K,Q) (3 hi/lo split combos), online softmax in exp2
// domain, P via LDS relayout, PV mfma. Final cross-wave combine via LDS.
__global__ __launch_bounds__(512, 2) void attn_kernel(
    const unsigned short* __restrict__ Qh, const unsigned short* __restrict__ Ql,
    const unsigned short* __restrict__ Kh, const unsigned short* __restrict__ Kl,
    const unsigned short* __restrict__ Vt, const float* __restrict__ bias,
    float* __restrict__ out)
{
  __shared__ unsigned p_lds[8][32][20];   // [wave][t 0..31][c-word, 16 used + 4 pad]
  __shared__ float acc_lds[8][32][32];    // combine: [wave][t][dy]
  __shared__ float2 ml_lds[8][2][16];     // combine: [wave][tb][t&15] = (m, l)

  const int tid = threadIdx.x;
  const int wid = tid >> 6, lane = tid & 63;
  const int lr = lane & 15, g = lane >> 4;
  const int tbase = blockIdx.x * 32;

  // Q fragments (MFMA B-operand): lane holds Q[tb*16+lr][f*32 + 8g .. +7]
  bf16x8 qh[2][2], ql[2][2];
  #pragma unroll
  for (int tb = 0; tb < 2; ++tb)
    #pragma unroll
    for (int f = 0; f < 2; ++f) {
      int off = (tbase + tb * 16 + lr) * 64 + f * 32 + 8 * g;
      qh[tb][f] = ldg8(Qh + off);
      ql[tb][f] = ldg8(Ql + off);
    }

  f32x4 acc[2][2];                        // [tb][dyb], D-layout row=t_rel=4g+r, col=dy
  #pragma unroll
  for (int a = 0; a < 2; ++a)
    #pragma unroll
    for (int d = 0; d < 2; ++d)
      acc[a][d] = (f32x4)(0.0f);
  float m0 = -1e30f, m1 = -1e30f, l0 = 0.f, l1 = 0.f;

  const int cstart = wid * 1024;
  for (int it = 0; it < 32; ++it) {
    const int c0 = cstart + it * 32;
    // K fragments (A-operand): lane holds K[c0+cb*16+lr][f*32 + 8g .. +7]
    bf16x8 kh[2][2], kl[2][2];
    #pragma unroll
    for (int cb = 0; cb < 2; ++cb)
      #pragma unroll
      for (int f = 0; f < 2; ++f) {
        int off = (c0 + cb * 16 + lr) * 64 + f * 32 + 8 * g;
        kh[cb][f] = ldg8(Kh + off);
        kl[cb][f] = ldg8(Kl + off);
      }
    // V fragments (B-operand for PV): lane holds V[c0+8g..+7][dyb*16+lr] = Vt rows
    bf16x8 vf[2];
    #pragma unroll
    for (int dyb = 0; dyb < 2; ++dyb)
      vf[dyb] = ldg8(Vt + (dyb * 16 + lr) * 8192 + c0 + 8 * g);

    // S^T[c][t], seeded with bias[c] through the C operand (elem r <-> c = cb*16+4g+r)
    f32x4 s[2][2];
    #pragma unroll
    for (int cb = 0; cb < 2; ++cb) {
      f32x4 bv = *reinterpret_cast<const f32x4*>(bias + c0 + cb * 16 + 4 * g);
      s[cb][0] = bv;
      s[cb][1] = bv;
    }
    #pragma unroll
    for (int cb = 0; cb < 2; ++cb)
      #pragma unroll
      for (int tb = 0; tb < 2; ++tb)
        #pragma unroll
        for (int f = 0; f < 2; ++f) {
          s[cb][tb] = __builtin_amdgcn_mfma_f32_16x16x32_bf16(kh[cb][f], qh[tb][f], s[cb][tb], 0, 0, 0);
          s[cb][tb] = __builtin_amdgcn_mfma_f32_16x16x32_bf16(kl[cb][f], qh[tb][f], s[cb][tb], 0, 0, 0);
          s[cb][tb] = __builtin_amdgcn_mfma_f32_16x16x32_bf16(kh[cb][f], ql[tb][f], s[cb][tb], 0, 0, 0);
        }

    // row (target) max over this 32-context tile; t = tb*16 + lr
    float tm0 = s[0][0][0], tm1 = s[0][1][0];
    #pragma unroll
    for (int cb = 0; cb < 2; ++cb)
      #pragma unroll
      for (int r = 0; r < 4; ++r) {
        tm0 = fmaxf(tm0, s[cb][0][r]);
        tm1 = fmaxf(tm1, s[cb][1][r]);
      }
    tm0 = fmaxf(tm0, __shfl_xor(tm0, 16, 64));
    tm0 = fmaxf(tm0, __shfl_xor(tm0, 32, 64));
    tm1 = fmaxf(tm1, __shfl_xor(tm1, 16, 64));
    tm1 = fmaxf(tm1, __shfl_xor(tm1, 32, 64));

    // defer-max: only rescale when the tile max outgrows running max by >4 (p <= 16)
    bool nos = (tm0 <= m0 + 4.f) && (tm1 <= m1 + 4.f);
    if (!__all(nos)) {
      float nm0 = fmaxf(m0, tm0), nm1 = fmaxf(m1, tm1);
      float sc0 = __builtin_amdgcn_exp2f(m0 - nm0);
      float sc1 = __builtin_amdgcn_exp2f(m1 - nm1);
      l0 *= sc0;
      l1 *= sc1;
      #pragma unroll
      for (int r = 0; r < 4; ++r) {
        float a0 = __shfl(sc0, 4 * g + r, 64);   // scale for acc row t_rel = 4g+r
        float a1 = __shfl(sc1, 4 * g + r, 64);
        acc[0][0][r] *= a0; acc[0][1][r] *= a0;
        acc[1][0][r] *= a1; acc[1][1][r] *= a1;
      }
      m0 = nm0;
      m1 = nm1;
    }

    // p = exp2(s - m); pack to bf16 pairs; l-sum uses the SAME rounded values
    unsigned pw0[2][2], pw1[2][2];
    float tl0 = 0.f, tl1 = 0.f;
    #pragma unroll
    for (int cb = 0; cb < 2; ++cb) {
      float p00 = __builtin_amdgcn_exp2f(s[cb][0][0] - m0);
      float p01 = __builtin_amdgcn_exp2f(s[cb][0][1] - m0);
      float p02 = __builtin_amdgcn_exp2f(s[cb][0][2] - m0);
      float p03 = __builtin_amdgcn_exp2f(s[cb][0][3] - m0);
      float p10 = __builtin_amdgcn_exp2f(s[cb][1][0] - m1);
      float p11 = __builtin_amdgcn_exp2f(s[cb][1][1] - m1);
      float p12 = __builtin_amdgcn_exp2f(s[cb][1][2] - m1);
      float p13 = __builtin_amdgcn_exp2f(s[cb][1][3] - m1);
      pw0[cb][0] = cvt_pk_bf16(p00, p01);
      pw0[cb][1] = cvt_pk_bf16(p02, p03);
      pw1[cb][0] = cvt_pk_bf16(p10, p11);
      pw1[cb][1] = cvt_pk_bf16(p12, p13);
      #pragma unroll
      for (int w = 0; w < 2; ++w) {
        tl0 += __uint_as_float(pw0[cb][w] << 16) + __uint_as_float(pw0[cb][w] & 0xffff0000u);
        tl1 += __uint_as_float(pw1[cb][w] << 16) + __uint_as_float(pw1[cb][w] & 0xffff0000u);
      }
    }
    tl0 += __shfl_xor(tl0, 16, 64);
    tl0 += __shfl_xor(tl0, 32, 64);
    tl1 += __shfl_xor(tl1, 16, 64);
    tl1 += __shfl_xor(tl1, 32, 64);
    l0 += tl0;
    l1 += tl1;

    // P relayout through wave-private LDS: write [t][c] pairs, read PV A-fragments
    #pragma unroll
    for (int cb = 0; cb < 2; ++cb) {
      uint2 wa; wa.x = pw0[cb][0]; wa.y = pw0[cb][1];
      *reinterpret_cast<uint2*>(&p_lds[wid][lr][cb * 8 + 2 * g]) = wa;
      uint2 wb; wb.x = pw1[cb][0]; wb.y = pw1[cb][1];
      *reinterpret_cast<uint2*>(&p_lds[wid][16 + lr][cb * 8 + 2 * g]) = wb;
    }
    bf16x8 pa0 = __builtin_bit_cast(bf16x8, *reinterpret_cast<const uint4*>(&p_lds[wid][lr][4 * g]));
    bf16x8 pa1 = __builtin_bit_cast(bf16x8, *reinterpret_cast<const uint4*>(&p_lds[wid][16 + lr][4 * g]));
    acc[0][0] = __builtin_amdgcn_mfma_f32_16x16x32_bf16(pa0, vf[0], acc[0][0], 0, 0, 0);
    acc[0][1] = __builtin_amdgcn_mfma_f32_16x16x32_bf16(pa0, vf[1], acc[0][1], 0, 0, 0);
    acc[1][0] = __builtin_amdgcn_mfma_f32_16x16x32_bf16(pa1, vf[0], acc[1][0], 0, 0, 0);
    acc[1][1] = __builtin_amdgcn_mfma_f32_16x16x32_bf16(pa1, vf[1], acc[1][1], 0, 0, 0);
  }

  // stage per-wave partials and combine across the 8 waves
  #pragma unroll
  for (int tb = 0; tb < 2; ++tb)
    #pragma unroll
    for (int dyb = 0; dyb < 2; ++dyb)
      #pragma unroll
      for (int r = 0; r < 4; ++r)
        acc_lds[wid][tb * 16 + 4 * g + r][dyb * 16 + lr] = acc[tb][dyb][r];
  if (g == 0) {
    ml_lds[wid][0][lr] = make_float2(m0, l0);
    ml_lds[wid][1][lr] = make_float2(m1, l1);
  }
  __syncthreads();

  for (int item = tid; item < 1024; item += 512) {
    int t = item >> 5, dy = item & 31;
    int tb = t >> 4, tr = t & 15;
    float M = -1e30f;
    #pragma unroll
    for (int w = 0; w < 8; ++w) M = fmaxf(M, ml_lds[w][tb][tr].x);
    float num = 0.f, den = 0.f;
    #pragma unroll
    for (int w = 0; w < 8; ++w) {
      float2 v = ml_lds[w][tb][tr];
      float e = __builtin_amdgcn_exp2f(v.x - M);
      num = fmaf(acc_lds[w][t][dy], e, num);
      den = fmaf(v.y, e, den);
    }
    out[(tbase + t) * 32 + dy] = num / den;
  }
}

extern "C" void kernel_launch(void* const* d_in, const int* in_sizes, int n_in,
                              void* d_out, int out_size, void* d_ws, size_t ws_size,
                              hipStream_t stream)
{
  const float* zc = (const float*)d_in[0];   // z_context (8192,64)
  const float* yc = (const float*)d_in[1];   // y_context (8192,32)
  const float* zt = (const float*)d_in[2];   // z_target  (8192,64)
  const float* W  = (const float*)d_in[3];   // W (64,64)

  unsigned short* Qh = (unsigned short*)d_ws;        // 8192*64
  unsigned short* Ql = Qh + 8192 * 64;
  unsigned short* Kh = Ql + 8192 * 64;
  unsigned short* Kl = Kh + 8192 * 64;
  unsigned short* Vt = Kl + 8192 * 64;               // 32*8192
  float* bias = (float*)(Vt + 32 * 8192);            // 8192 f32  (total ~4.75 MB)

  prep_kernel<<<7168, 256, 0, stream>>>(zc, yc, zt, W, Qh, Ql, Kh, Kl, Vt, bias);
  attn_kernel<<<256, 512, 0, stream>>>(Qh, Ql, Kh, Kl, Vt, bias, (float*)d_out);
}

// Round 4
// 109.343 us; speedup vs baseline: 1.0637x; 1.0637x over previous
//
#include <hip/hip_runtime.h>
#include <hip/hip_bf16.h>

// Interpolator == attention: out = softmax_c(z_t^T (W+W^T) z_c - q_cc[c]) @ y_context
// Msym = log2e*(W+W^T) (f32, precomputed once)
// Q = z_target @ Msym  (split hi/lo bf16; log2e folded in)
// K = z_context        (split hi/lo bf16)
// bias[c] = -0.5 * z_c^T Msym z_c  (f32)  == -log2e * z_c^T W z_c
// V^T bf16 [32][8192]; denominator computed via ones-fragment PV MFMA.

typedef float f32x4 __attribute__((ext_vector_type(4)));
typedef __bf16 bf16x8 __attribute__((ext_vector_type(8)));

#define LOG2E 1.4426950408889634f

static __device__ __forceinline__ unsigned short f2bf(float x) {
  unsigned u = __float_as_uint(x);
  u += 0x7fffu + ((u >> 16) & 1u);   // RNE
  return (unsigned short)(u >> 16);
}
static __device__ __forceinline__ float bf2f(unsigned short h) {
  return __uint_as_float(((unsigned)h) << 16);
}
static __device__ __forceinline__ bf16x8 ldg8(const unsigned short* p) {
  uint4 u = *reinterpret_cast<const uint4*>(p);
  return __builtin_bit_cast(bf16x8, u);
}
static __device__ __forceinline__ unsigned cvt_pk_bf16(float lo, float hi) {
  unsigned r;
  asm("v_cvt_pk_bf16_f32 %0, %1, %2" : "=v"(r) : "v"(lo), "v"(hi));
  return r;
}

__global__ void msym_kernel(const float* __restrict__ W, float* __restrict__ Msym) {
  int idx = blockIdx.x * 256 + threadIdx.x;   // 16 blocks -> 4096 elems
  int k = idx >> 6, d = idx & 63;
  Msym[idx] = LOG2E * (W[k * 64 + d] + W[d * 64 + k]);
}

__global__ void prep_kernel(const float* __restrict__ zc, const float* __restrict__ yc,
                            const float* __restrict__ zt, const float* __restrict__ Msym,
                            unsigned short* __restrict__ Qh, unsigned short* __restrict__ Ql,
                            unsigned short* __restrict__ Kh, unsigned short* __restrict__ Kl,
                            unsigned short* __restrict__ Vt, float* __restrict__ bias)
{
  int b = blockIdx.x, tid = threadIdx.x;
  if (b < 2048) {                       // Q = z_t @ Msym, hi/lo split (coalesced Msym reads)
    int idx = b * 256 + tid;
    int t = idx >> 6, d = idx & 63;
    const float* z = zt + t * 64;
    float q = 0.f;
    #pragma unroll 8
    for (int k = 0; k < 64; ++k) q = fmaf(z[k], Msym[k * 64 + d], q);
    unsigned short h = f2bf(q);
    Qh[idx] = h;
    Ql[idx] = f2bf(q - bf2f(h));
  } else if (b < 4096) {                // K hi/lo split
    int idx = (b - 2048) * 256 + tid;
    float v = zc[idx];
    unsigned short h = f2bf(v);
    Kh[idx] = h;
    Kl[idx] = f2bf(v - bf2f(h));
  } else if (b < 6144) {                // bias[c] = -0.5 * z_c^T Msym z_c, one wave per c
    int c = (b - 4096) * 4 + (tid >> 6), j = tid & 63;
    const float* z = zc + c * 64;
    float cs = 0.f;
    #pragma unroll 8
    for (int i = 0; i < 64; ++i) cs = fmaf(z[i], Msym[i * 64 + j], cs);
    float part = cs * z[j];
    #pragma unroll
    for (int off = 32; off >= 1; off >>= 1) part += __shfl_xor(part, off, 64);
    if (j == 0) bias[c] = -0.5f * part;
  } else {                              // V^T bf16
    int idx = (b - 6144) * 256 + tid;
    int dy = idx >> 13, c = idx & 8191;
    Vt[dy * 8192 + c] = f2bf(yc[c * 32 + dy]);
  }
}

// 256 blocks x 1024 threads (16 waves). Block owns 32 targets; wave w owns contexts
// [w*512,(w+1)*512), 16 iterations of 32 contexts. Denominator l accumulated by an
// extra ones-fragment MFMA (acc layout), so the common-case softmax path has ZERO
// cross-lane ops (per-lane defer-max check; full reduce only on rescale events).
__global__ __launch_bounds__(1024, 4) void attn_kernel(
    const unsigned short* __restrict__ Qh, const unsigned short* __restrict__ Ql,
    const unsigned short* __restrict__ Kh, const unsigned short* __restrict__ Kl,
    const unsigned short* __restrict__ Vt, const float* __restrict__ bias,
    float* __restrict__ out)
{
  __shared__ unsigned p_lds[16][32][20];   // [wave][t 0..31][c-word, 16 used + 4 pad]
  __shared__ float acc_lds[16][32][32];    // combine: [wave][t][dy]
  __shared__ float2 ml_lds[16][2][16];     // combine: [wave][tb][t&15] = (m, l)

  const int tid = threadIdx.x;
  const int wid = tid >> 6, lane = tid & 63;
  const int lr = lane & 15, g = lane >> 4;
  const int tbase = blockIdx.x * 32;

  // Q fragments (MFMA B-operand): lane holds Q[tb*16+lr][f*32 + 8g .. +7]
  bf16x8 qh[2][2], ql[2][2];
  #pragma unroll
  for (int tb = 0; tb < 2; ++tb)
    #pragma unroll
    for (int f = 0; f < 2; ++f) {
      int off = (tbase + tb * 16 + lr) * 64 + f * 32 + 8 * g;
      qh[tb][f] = ldg8(Qh + off);
      ql[tb][f] = ldg8(Ql + off);
    }

  // ones fragment for the denominator MFMA (bf16 1.0 = 0x3F80)
  uint4 ones_bits = make_uint4(0x3F803F80u, 0x3F803F80u, 0x3F803F80u, 0x3F803F80u);
  bf16x8 vones = __builtin_bit_cast(bf16x8, ones_bits);

  f32x4 acc[2][2];                        // [tb][dyb], D-layout row=t_rel=4g+r, col=dy
  f32x4 accl[2];                          // denominator in acc layout (all cols equal)
  #pragma unroll
  for (int a = 0; a < 2; ++a) {
    #pragma unroll
    for (int d = 0; d < 2; ++d) acc[a][d] = (f32x4)(0.0f);
    accl[a] = (f32x4)(0.0f);
  }
  float m0 = -1e30f, m1 = -1e30f;

  const int cstart = wid * 512;
  for (int it = 0; it < 16; ++it) {
    const int c0 = cstart + it * 32;
    // K fragments (A-operand): lane holds K[c0+cb*16+lr][f*32 + 8g .. +7]
    bf16x8 kh[2][2], kl[2][2];
    #pragma unroll
    for (int cb = 0; cb < 2; ++cb)
      #pragma unroll
      for (int f = 0; f < 2; ++f) {
        int off = (c0 + cb * 16 + lr) * 64 + f * 32 + 8 * g;
        kh[cb][f] = ldg8(Kh + off);
        kl[cb][f] = ldg8(Kl + off);
      }
    // V fragments (B-operand for PV): lane holds V[c0+8g..+7][dyb*16+lr]
    bf16x8 vf[2];
    #pragma unroll
    for (int dyb = 0; dyb < 2; ++dyb)
      vf[dyb] = ldg8(Vt + (dyb * 16 + lr) * 8192 + c0 + 8 * g);

    // S^T[c][t], seeded with bias[c] through the C operand (elem r <-> c = cb*16+4g+r)
    f32x4 s[2][2];
    #pragma unroll
    for (int cb = 0; cb < 2; ++cb) {
      f32x4 bv = *reinterpret_cast<const f32x4*>(bias + c0 + cb * 16 + 4 * g);
      s[cb][0] = bv;
      s[cb][1] = bv;
    }
    #pragma unroll
    for (int cb = 0; cb < 2; ++cb)
      #pragma unroll
      for (int tb = 0; tb < 2; ++tb)
        #pragma unroll
        for (int f = 0; f < 2; ++f) {
          s[cb][tb] = __builtin_amdgcn_mfma_f32_16x16x32_bf16(kh[cb][f], qh[tb][f], s[cb][tb], 0, 0, 0);
          s[cb][tb] = __builtin_amdgcn_mfma_f32_16x16x32_bf16(kl[cb][f], qh[tb][f], s[cb][tb], 0, 0, 0);
          s[cb][tb] = __builtin_amdgcn_mfma_f32_16x16x32_bf16(kh[cb][f], ql[tb][f], s[cb][tb], 0, 0, 0);
        }

    // per-lane tile max (no cross-lane ops in common case)
    float tm0 = s[0][0][0], tm1 = s[0][1][0];
    #pragma unroll
    for (int cb = 0; cb < 2; ++cb)
      #pragma unroll
      for (int r = 0; r < 4; ++r) {
        tm0 = fmaxf(tm0, s[cb][0][r]);
        tm1 = fmaxf(tm1, s[cb][1][r]);
      }
    // defer-max: only rescale when local max outgrows running max by >8 (p <= 256)
    bool nos = (tm0 <= m0 + 8.f) && (tm1 <= m1 + 8.f);
    if (!__all(nos)) {
      tm0 = fmaxf(tm0, __shfl_xor(tm0, 16, 64));
      tm0 = fmaxf(tm0, __shfl_xor(tm0, 32, 64));
      tm1 = fmaxf(tm1, __shfl_xor(tm1, 16, 64));
      tm1 = fmaxf(tm1, __shfl_xor(tm1, 32, 64));
      float nm0 = fmaxf(m0, tm0), nm1 = fmaxf(m1, tm1);
      float sc0 = __builtin_amdgcn_exp2f(m0 - nm0);
      float sc1 = __builtin_amdgcn_exp2f(m1 - nm1);
      #pragma unroll
      for (int r = 0; r < 4; ++r) {
        float a0 = __shfl(sc0, 4 * g + r, 64);   // scale for acc row t_rel = 4g+r
        float a1 = __shfl(sc1, 4 * g + r, 64);
        acc[0][0][r] *= a0; acc[0][1][r] *= a0; accl[0][r] *= a0;
        acc[1][0][r] *= a1; acc[1][1][r] *= a1; accl[1][r] *= a1;
      }
      m0 = nm0;
      m1 = nm1;
    }

    // p = exp2(s - m); pack to bf16 pairs (denominator comes from the ones-MFMA)
    unsigned pw0[2][2], pw1[2][2];
    #pragma unroll
    for (int cb = 0; cb < 2; ++cb) {
      float p00 = __builtin_amdgcn_exp2f(s[cb][0][0] - m0);
      float p01 = __builtin_amdgcn_exp2f(s[cb][0][1] - m0);
      float p02 = __builtin_amdgcn_exp2f(s[cb][0][2] - m0);
      float p03 = __builtin_amdgcn_exp2f(s[cb][0][3] - m0);
      float p10 = __builtin_amdgcn_exp2f(s[cb][1][0] - m1);
      float p11 = __builtin_amdgcn_exp2f(s[cb][1][1] - m1);
      float p12 = __builtin_amdgcn_exp2f(s[cb][1][2] - m1);
      float p13 = __builtin_amdgcn_exp2f(s[cb][1][3] - m1);
      pw0[cb][0] = cvt_pk_bf16(p00, p01);
      pw0[cb][1] = cvt_pk_bf16(p02, p03);
      pw1[cb][0] = cvt_pk_bf16(p10, p11);
      pw1[cb][1] = cvt_pk_bf16(p12, p13);
    }

    // P relayout through wave-private LDS: write [t][c] pairs, read PV A-fragments
    #pragma unroll
    for (int cb = 0; cb < 2; ++cb) {
      uint2 wa; wa.x = pw0[cb][0]; wa.y = pw0[cb][1];
      *reinterpret_cast<uint2*>(&p_lds[wid][lr][cb * 8 + 2 * g]) = wa;
      uint2 wb; wb.x = pw1[cb][0]; wb.y = pw1[cb][1];
      *reinterpret_cast<uint2*>(&p_lds[wid][16 + lr][cb * 8 + 2 * g]) = wb;
    }
    bf16x8 pa0 = __builtin_bit_cast(bf16x8, *reinterpret_cast<const uint4*>(&p_lds[wid][lr][4 * g]));
    bf16x8 pa1 = __builtin_bit_cast(bf16x8, *reinterpret_cast<const uint4*>(&p_lds[wid][16 + lr][4 * g]));
    acc[0][0] = __builtin_amdgcn_mfma_f32_16x16x32_bf16(pa0, vf[0], acc[0][0], 0, 0, 0);
    acc[0][1] = __builtin_amdgcn_mfma_f32_16x16x32_bf16(pa0, vf[1], acc[0][1], 0, 0, 0);
    accl[0]   = __builtin_amdgcn_mfma_f32_16x16x32_bf16(pa0, vones, accl[0], 0, 0, 0);
    acc[1][0] = __builtin_amdgcn_mfma_f32_16x16x32_bf16(pa1, vf[0], acc[1][0], 0, 0, 0);
    acc[1][1] = __builtin_amdgcn_mfma_f32_16x16x32_bf16(pa1, vf[1], acc[1][1], 0, 0, 0);
    accl[1]   = __builtin_amdgcn_mfma_f32_16x16x32_bf16(pa1, vones, accl[1], 0, 0, 0);
  }

  // stage per-wave partials and combine across the 16 waves
  #pragma unroll
  for (int tb = 0; tb < 2; ++tb)
    #pragma unroll
    for (int dyb = 0; dyb < 2; ++dyb)
      #pragma unroll
      for (int r = 0; r < 4; ++r)
        acc_lds[wid][tb * 16 + 4 * g + r][dyb * 16 + lr] = acc[tb][dyb][r];
  if (g == 0) {
    ml_lds[wid][0][lr].x = m0;
    ml_lds[wid][1][lr].x = m1;
  }
  if (lr == 0) {
    #pragma unroll
    for (int r = 0; r < 4; ++r) {
      ml_lds[wid][0][4 * g + r].y = accl[0][r];   // all cols equal; col 0 value
      ml_lds[wid][1][4 * g + r].y = accl[1][r];
    }
  }
  __syncthreads();

  {
    int t = tid >> 5, dy = tid & 31;
    int tb = t >> 4, tr = t & 15;
    float M = -1e30f;
    #pragma unroll
    for (int w = 0; w < 16; ++w) M = fmaxf(M, ml_lds[w][tb][tr].x);
    float num = 0.f, den = 0.f;
    #pragma unroll
    for (int w = 0; w < 16; ++w) {
      float2 v = ml_lds[w][tb][tr];
      float e = __builtin_amdgcn_exp2f(v.x - M);
      num = fmaf(acc_lds[w][t][dy], e, num);
      den = fmaf(v.y, e, den);
    }
    out[(tbase + t) * 32 + dy] = num / den;
  }
}

extern "C" void kernel_launch(void* const* d_in, const int* in_sizes, int n_in,
                              void* d_out, int out_size, void* d_ws, size_t ws_size,
                              hipStream_t stream)
{
  const float* zc = (const float*)d_in[0];   // z_context (8192,64)
  const float* yc = (const float*)d_in[1];   // y_context (8192,32)
  const float* zt = (const float*)d_in[2];   // z_target  (8192,64)
  const float* W  = (const float*)d_in[3];   // W (64,64)

  unsigned short* Qh = (unsigned short*)d_ws;        // 8192*64
  unsigned short* Ql = Qh + 8192 * 64;
  unsigned short* Kh = Ql + 8192 * 64;
  unsigned short* Kl = Kh + 8192 * 64;
  unsigned short* Vt = Kl + 8192 * 64;               // 32*8192
  float* bias = (float*)(Vt + 32 * 8192);            // 8192 f32
  float* Msym = bias + 8192;                         // 4096 f32 (total ~4.8 MB)

  msym_kernel<<<16, 256, 0, stream>>>(W, Msym);
  prep_kernel<<<7168, 256, 0, stream>>>(zc, yc, zt, Msym, Qh, Ql, Kh, Kl, Vt, bias);
  attn_kernel<<<256, 1024, 0, stream>>>(Qh, Ql, Kh, Kl, Vt, bias, (float*)d_out);
}